// Round 4
// baseline (3533.479 us; speedup 1.0000x reference)
//
#include <hip/hip_runtime.h>
#include <hip/hip_bf16.h>

// B=32, T=2048, D=256, H=256, CS=32, N=8, G=4H+2N=1040.
// Scan over BATCH axis (32 steps), carry (T,H). Backward dir = col-reversed W_ih.
#define B_  32
#define T_  2048
#define D_  256
#define H_  256
#define G_  1040
#define GP  1088   // 17*64
#define KK  512    // D + H

#define STRA 520   // A LDS row stride (shorts): 512+8 pad (bank spread)
#define STRB 36    // W-slice LDS row stride (shorts): 32+4 pad
#define STRG 1092  // gates LDS row stride (floats): 1088+4 pad

using bf16   = __hip_bfloat16;
using short8 = __attribute__((ext_vector_type(8))) short;
using f32x4  = __attribute__((ext_vector_type(4))) float;

__device__ inline float sigmoidf_(float v) { return 1.f / (1.f + __expf(-v)); }
__device__ inline float tanh_(float v) {
  v = fminf(fmaxf(v, -15.f), 15.f);
  float e = __expf(2.f * v);
  return (e - 1.f) / (e + 1.f);
}
__device__ inline float bf2f(unsigned short u) {
  union { unsigned int i; float f; } c; c.i = ((unsigned int)u) << 16; return c.f;
}
__device__ inline float ldF(const void* p, size_t i, int isf) {
  return isf ? ((const float*)p)[i] : bf2f(((const unsigned short*)p)[i]);
}

// meta: [0]=is_fp32, [8+b]=seq_len[b], [40+b]=row base[b]
__global__ __launch_bounds__(256) void detect_prep(
    const unsigned short* __restrict__ xh, const int* __restrict__ sli,
    int* __restrict__ meta)
{
  __shared__ int s_bad;
  if (threadIdx.x == 0) s_bad = 0;
  __syncthreads();
  int bad = 0;
  for (int i = threadIdx.x; i < 1024; i += 256) {
    float f = bf2f(xh[i]);
    if (!(fabsf(f) < 100.f)) bad = 1;
  }
  if (bad) atomicOr(&s_bad, 1);
  __syncthreads();
  if (threadIdx.x == 0) {
    meta[0] = s_bad;
    bool is64 = true;
    for (int i = 1; i < 32; i += 2) if (sli[i] != 0) is64 = false;
    int base = 0;
    for (int b = 0; b < B_; ++b) {
      int v = is64 ? sli[2 * b] : sli[b];
      meta[8 + b]  = v;
      meta[40 + b] = base;
      base += v;
    }
  }
}

__global__ __launch_bounds__(256) void convert_x(
    const void* __restrict__ x, bf16* __restrict__ xbuf,
    const int* __restrict__ meta)
{
  const int isf = meta[0];
  size_t i0 = ((size_t)blockIdx.x * 256 + threadIdx.x) * 4;
  if (i0 >= (size_t)B_ * T_ * D_) return;
  #pragma unroll
  for (int j = 0; j < 4; ++j)
    xbuf[i0 + j] = __float2bfloat16(ldF(x, i0 + j, isf));
}

// Wcat[2][GP][KK]: dir0 [W_ih | W_hh]; dir1 [W_ih cols reversed | W_hh]; pad 0.
__global__ __launch_bounds__(256) void build_wcat(
    const void* __restrict__ W_ih, const void* __restrict__ W_hh,
    bf16* __restrict__ Wcat, const int* __restrict__ meta)
{
  const int isf = meta[0];
  int idx = blockIdx.x * 256 + threadIdx.x;
  if (idx >= 2 * GP * KK) return;
  int k = idx & (KK - 1);
  int g = (idx / KK) % GP;
  int d = idx / (KK * GP);
  float v;
  if (g >= G_)      v = 0.f;
  else if (k < D_)  v = ldF(W_ih, (size_t)g * D_ + ((d == 0) ? k : (D_ - 1 - k)), isf);
  else              v = ldF(W_hh, (size_t)g * H_ + (k - D_), isf);
  Wcat[idx] = __float2bfloat16(v);
}

__global__ __launch_bounds__(256) void build_bsum(
    const void* __restrict__ b_ih, const void* __restrict__ b_hh,
    float* __restrict__ bsum, const int* __restrict__ meta)
{
  const int isf = meta[0];
  int i = blockIdx.x * 256 + threadIdx.x;
  if (i < G_) bsum[i] = ldF(b_ih, i, isf) + ldF(b_hh, i, isf);
}

// ---------------------------------------------------------------------------
// Fused per-step kernel: block = 32 rows (one dir) x full 1088 gate cols.
// gates = [x[b]|h] @ Wcat[d]^T  (K=512, MFMA)  -> LDS -> cumsoftmax/cell -> h,c,out.
// 128 blocks x 512 threads (8 waves: 2 M x 4 N; 17 frags/wave).
// ---------------------------------------------------------------------------
__global__ __launch_bounds__(512) void step_fused(
    const bf16* __restrict__ xbuf,   // (B,T,D)
    const bf16* __restrict__ Wcat,   // (2,GP,KK)
    bf16* __restrict__ hbuf,         // (2,T,H) bf16 (read prev, write new)
    float* __restrict__ cbuf,        // (2,T,H) fp32
    const float* __restrict__ bsum,  // (G)
    void* __restrict__ out,
    const int* __restrict__ meta,
    int b)
{
  __shared__ __align__(16) char smem[32 * STRA * 2 + GP * STRB * 2]; // 33.3 + 78.3 KB
  bf16*  As = (bf16*)smem;                          // 32 x STRA
  bf16*  Bs = (bf16*)(smem + 32 * STRA * 2);        // GP x STRB
  float* gl = (float*)(smem + 32 * STRA * 2);       // 16 x STRG (aliases Bs)

  const int tid  = threadIdx.x;
  const int blk  = blockIdx.x;       // 0..127
  const int d    = blk >> 6;
  const int r0   = (blk & 63) * 32;  // row tile base (t index)
  const int w    = tid >> 6;         // 0..7
  const int lane = tid & 63;
  const int mw   = w & 1;            // M-half
  const int nw   = w >> 1;           // N-quarter 0..3
  const int m15  = lane & 15;
  const int kq   = (lane >> 4) * 8;

  // ---- stage A = [x rows | h rows] : 32 x 512 bf16 ----
  #pragma unroll
  for (int it = 0; it < 4; ++it) {
    int idx = it * 512 + tid;          // 0..2047 = 32 rows x 64 chunks
    int r  = idx >> 6;
    int c  = (idx & 63) * 8;
    const bf16* src = (c < D_)
        ? xbuf + ((size_t)b * T_ + r0 + r) * D_ + c
        : hbuf + ((size_t)d * T_ + r0 + r) * H_ + (c - D_);
    *(short8*)&As[r * STRA + c] = *(const short8*)src;
  }

  f32x4 acc[17];
  #pragma unroll
  for (int f = 0; f < 17; ++f) acc[f] = (f32x4){0.f, 0.f, 0.f, 0.f};

  const bf16* wmat = Wcat + (size_t)d * GP * KK;

  for (int ks = 0; ks < 16; ++ks) {
    const int k0 = ks * 32;
    __syncthreads();   // A staged (ks=0) / prior Bs reads complete
    // stage W k-slice: GP rows x 32 k  (4352 short8 chunks over 512 threads)
    #pragma unroll
    for (int it = 0; it < 9; ++it) {
      int idx = it * 512 + tid;
      if (idx < GP * 4) {
        int g = idx >> 2;
        int c = (idx & 3) * 8;
        *(short8*)&Bs[g * STRB + c] = *(const short8*)&wmat[(size_t)g * KK + k0 + c];
      }
    }
    __syncthreads();

    short8 af = *(const short8*)&As[(mw * 16 + m15) * STRA + k0 + kq];
    #pragma unroll
    for (int f = 0; f < 17; ++f) {
      short8 bfr = *(const short8*)&Bs[(nw * 272 + f * 16 + m15) * STRB + kq];
      acc[f] = __builtin_amdgcn_mfma_f32_16x16x32_bf16(af, bfr, acc[f], 0, 0, 0);
    }
  }

  // ---- epilogue: two M-phases through LDS (fp32 gates), cell math fused ----
  const int isf    = meta[0];
  const int len_s  = meta[8 + b];
  const int base_s = meta[40 + b];

  for (int ph = 0; ph < 2; ++ph) {
    __syncthreads();   // Bs / previous-phase gl reads complete
    if (mw == ph) {
      const int grow = (lane >> 4) * 4;
      #pragma unroll
      for (int f = 0; f < 17; ++f) {
        const int gcol = nw * 272 + f * 16 + m15;
        #pragma unroll
        for (int r = 0; r < 4; ++r)
          gl[(grow + r) * STRG + gcol] = acc[f][r];
      }
    }
    __syncthreads();

    // cell for 16 rows; thread = (row = tid/32, e0 = tid%32), e = e0 + 32j
    const int lrow = tid >> 5;          // 0..15
    const int e0   = tid & 31;
    const int t    = r0 + ph * 16 + lrow;
    const float* g = &gl[lrow * STRG];

    float gi[16];
    #pragma unroll
    for (int i = 0; i < 16; ++i) gi[i] = g[i] + bsum[i];
    float m1 = gi[0], m2 = gi[8];
    #pragma unroll
    for (int i = 1; i < 8; ++i) { m1 = fmaxf(m1, gi[i]); m2 = fmaxf(m2, gi[8 + i]); }
    float p1[8], p2[8], s1 = 0.f, s2 = 0.f;
    #pragma unroll
    for (int i = 0; i < 8; ++i) {
      s1 += __expf(gi[i] - m1);     p1[i] = s1;
      s2 += __expf(gi[8 + i] - m2); p2[i] = s2;
    }

    #pragma unroll
    for (int j = 0; j < 8; ++j) {
      const int e = e0 + 32 * j;       // chunk n = j
      const float cin = 1.f - p1[j] / s1;
      const float cfg = p2[j] / s2;
      const float og = sigmoidf_(g[16 + e]  + bsum[16 + e]);
      const float cg = tanh_   (g[272 + e]  + bsum[272 + e]);
      const float ig = sigmoidf_(g[528 + e] + bsum[528 + e]);
      const float fg = sigmoidf_(g[784 + e] + bsum[784 + e]);
      const float ov = cfg * cin;
      const float f2 = fg * ov + (cfg - ov);
      const float i2 = ig * ov + (cin - ov);
      const size_t cidx = ((size_t)d * T_ + t) * H_ + e;
      const float cy = f2 * cbuf[cidx] + i2 * cg;
      cbuf[cidx] = cy;
      const float hy = og * tanh_(cy);
      hbuf[cidx] = __float2bfloat16(hy);
      if (t < len_s) {
        const size_t o = (size_t)(base_s + t) * (2 * H_) + (size_t)d * H_ + e;
        if (isf) ((float*)out)[o] = hy;
        else     ((bf16*)out)[o]  = __float2bfloat16(hy);
      }
    }
  }
}

// ---------------------------------------------------------------------------
extern "C" void kernel_launch(void* const* d_in, const int* in_sizes, int n_in,
                              void* d_out, int out_size, void* d_ws, size_t ws_size,
                              hipStream_t stream)
{
  const void* x    = d_in[0];
  const int*  sl   = (const int*)d_in[1];
  const void* W_ih = d_in[2];
  const void* b_ih = d_in[3];
  const void* W_hh = d_in[4];
  const void* b_hh = d_in[5];

  char* ws = (char*)d_ws;
  size_t off = 0;
  auto alloc = [&](size_t bytes) {
    void* p = ws + off;
    off = (off + bytes + 255) & ~(size_t)255;
    return p;
  };
  int*   meta = (int*)  alloc(128 * sizeof(int));
  bf16*  xbuf = (bf16*) alloc((size_t)B_ * T_ * D_ * sizeof(bf16));   // 32 MB
  bf16*  Wcat = (bf16*) alloc((size_t)2 * GP * KK * sizeof(bf16));    // 2.2 MB
  bf16*  hbuf = (bf16*) alloc((size_t)2 * T_ * H_ * sizeof(bf16));    // 2 MB
  float* cbuf = (float*)alloc((size_t)2 * T_ * H_ * sizeof(float));   // 4 MB
  float* bsum = (float*)alloc((size_t)G_ * sizeof(float));

  hipMemsetAsync(hbuf, 0, (size_t)2 * T_ * H_ * sizeof(bf16), stream);
  hipMemsetAsync(cbuf, 0, (size_t)2 * T_ * H_ * sizeof(float), stream);

  detect_prep<<<1, 256, 0, stream>>>((const unsigned short*)x, sl, meta);
  build_bsum<<<(G_ + 255) / 256, 256, 0, stream>>>(b_ih, b_hh, bsum, meta);
  convert_x<<<(B_ * T_ * D_ / 4 + 255) / 256, 256, 0, stream>>>(x, xbuf, meta);
  build_wcat<<<(2 * GP * KK + 255) / 256, 256, 0, stream>>>(W_ih, W_hh, Wcat, meta);

  for (int b = 0; b < B_; ++b)
    step_fused<<<128, 512, 0, stream>>>(xbuf, Wcat, hbuf, cbuf, bsum, d_out, meta, b);
}

// Round 5
// 849.290 us; speedup vs baseline: 4.1605x; 4.1605x over previous
//
#include <hip/hip_runtime.h>
#include <hip/hip_bf16.h>

// B=32, T=2048, D=256, H=256, CS=32, N=8, G=4H+2N=1040.
// Scan over BATCH axis (32 steps), carry (T,H). Backward dir = col-reversed W_ih.
#define B_  32
#define T_  2048
#define D_  256
#define H_  256
#define G_  1040
#define KK  512    // D + H

#define NSL 8      // e-slices of width 32 (== CS; slice s == chunk n)
#define NRB 16     // row-blocks of 128 rows
#define NMB 4      // mblocks (1 per wave) of 32 rows
#define NKB 32     // K16 chunks over KK=512
#define NF  5      // B col-frags: og,cg,ig,fg (32 cols) + [cols 0..15 | zeros]

using bf16   = __hip_bfloat16;
using short8 = __attribute__((ext_vector_type(8))) short;
using f32x16 = __attribute__((ext_vector_type(16))) float;

__device__ inline float sigmoidf_(float v) { return 1.f / (1.f + __expf(-v)); }
__device__ inline float tanh_(float v) {
  v = fminf(fmaxf(v, -15.f), 15.f);
  float e = __expf(2.f * v);
  return (e - 1.f) / (e + 1.f);
}
__device__ inline float bf2f(unsigned short u) {
  union { unsigned int i; float f; } c; c.i = ((unsigned int)u) << 16; return c.f;
}
__device__ inline float ldF(const void* p, size_t i, int isf) {
  return isf ? ((const float*)p)[i] : bf2f(((const unsigned short*)p)[i]);
}
__device__ inline short f2bs(float v) {
  bf16 h = __float2bfloat16(v);
  return *(short*)&h;
}

// meta: [0]=is_fp32, [8+b]=seq_len[b], [40+b]=row base[b]
__global__ __launch_bounds__(256) void detect_prep(
    const unsigned short* __restrict__ xh, const int* __restrict__ sli,
    int* __restrict__ meta)
{
  __shared__ int s_bad;
  if (threadIdx.x == 0) s_bad = 0;
  __syncthreads();
  int bad = 0;
  for (int i = threadIdx.x; i < 1024; i += 256) {
    float f = bf2f(xh[i]);
    if (!(fabsf(f) < 100.f)) bad = 1;
  }
  if (bad) atomicOr(&s_bad, 1);
  __syncthreads();
  if (threadIdx.x == 0) {
    meta[0] = s_bad;
    bool is64 = true;
    for (int i = 1; i < 32; i += 2) if (sli[i] != 0) is64 = false;
    int base = 0;
    for (int b = 0; b < B_; ++b) {
      int v = is64 ? sli[2 * b] : sli[b];
      meta[8 + b]  = v;
      meta[40 + b] = base;
      base += v;
    }
  }
}

__global__ __launch_bounds__(256) void build_bsum(
    const void* __restrict__ b_ih, const void* __restrict__ b_hh,
    float* __restrict__ bsum, const int* __restrict__ meta)
{
  const int isf = meta[0];
  int i = blockIdx.x * 256 + threadIdx.x;
  if (i < G_) bsum[i] = ldF(b_ih, i, isf) + ldF(b_hh, i, isf);
}

// xs[b][rb(16)][kbx(16)][mb(4)][lane(64)][8]: A-frag image for 32x32x16
//   lane -> (m = lane&31, k8 = lane>>5); element (t = rb*128+mb*32+m, k = kbx*16+k8*8+j)
__global__ __launch_bounds__(256) void build_xs(
    const void* __restrict__ x, bf16* __restrict__ xs,
    const int* __restrict__ meta)
{
  const int isf = meta[0];
  size_t idx = (size_t)blockIdx.x * 256 + threadIdx.x;   // over B*T*D/8
  if (idx >= (size_t)B_ * T_ * D_ / 8) return;
  const int lane = idx & 63;
  const int mb   = (idx >> 6) & 3;
  const int kbx  = (idx >> 8) & 15;
  const int rb   = (idx >> 12) & 15;
  const int b    = idx >> 16;
  const int t  = rb * 128 + mb * 32 + (lane & 31);
  const int k0 = kbx * 16 + (lane >> 5) * 8;
  const size_t src = ((size_t)b * T_ + t) * D_ + k0;
  short8 v;
  #pragma unroll
  for (int j = 0; j < 8; ++j) v[j] = f2bs(ldF(x, src + j, isf));
  *(short8*)(xs + idx * 8) = v;
}

// Wsw[d][s][kb(32)][f(5)][lane(64)][8]: B-frag image for 32x32x16
//   lane -> (n = lane&31, k8 = lane>>5); gate col g: f<4 -> 16+f*256+s*32+n,
//   f==4 -> n<16 ? n : zero-pad.  k = kb*16+k8*8+j; k<256 -> W_ih (dir1 reversed), else W_hh.
__global__ __launch_bounds__(256) void build_wsw(
    const void* __restrict__ W_ih, const void* __restrict__ W_hh,
    bf16* __restrict__ Wsw, const int* __restrict__ meta)
{
  const int isf = meta[0];
  int idx = blockIdx.x * 256 + threadIdx.x;   // over 2*8*32*5*64 = 163840
  if (idx >= 2 * NSL * NKB * NF * 64) return;
  const int lane = idx & 63;
  const int f    = (idx >> 6) % NF;
  const int kb   = (idx / (64 * NF)) % NKB;
  const int sl   = (idx / (64 * NF * NKB)) % NSL;
  const int d    = idx / (64 * NF * NKB * NSL);
  const int n    = lane & 31;
  const int k0   = kb * 16 + (lane >> 5) * 8;
  const int g = (f < 4) ? (16 + f * H_ + sl * 32 + n) : ((n < 16) ? n : -1);
  short8 v;
  #pragma unroll
  for (int j = 0; j < 8; ++j) {
    float val = 0.f;
    const int k = k0 + j;
    if (g >= 0)
      val = (k < D_) ? ldF(W_ih, (size_t)g * D_ + (d ? (D_ - 1 - k) : k), isf)
                     : ldF(W_hh, (size_t)g * H_ + (k - D_), isf);
    v[j] = f2bs(val);
  }
  *(short8*)(Wsw + (size_t)idx * 8) = v;
}

// ---------------------------------------------------------------------------
// Fused step: block = (dir, e-slice s, rowblock rb of 128 rows); 4 waves (M=32).
// gates = [x|h] @ W^T via 32x32x16 MFMA (5 col-frags), cell math in-register.
// hs: h in A-frag image layout [d][rb][kbh(16)][mb][lane][8] (read as GEMM input next step).
// cs: block-private c slab [d][s][rb][mb][reg(16)][lane(64)] fp32.
// ---------------------------------------------------------------------------
__global__ __launch_bounds__(256) void step_fused(
    const bf16* __restrict__ xs, const bf16* __restrict__ Wsw,
    bf16* __restrict__ hs, float* __restrict__ cs,
    const float* __restrict__ bsum, void* __restrict__ out,
    const int* __restrict__ meta, int b)
{
  __shared__ __align__(16) bf16 Bsm[2][NF][64 * 8];  // 10 KB (double-buffered W chunk)
  __shared__ float gsm[128][16];                     // 8 KB  (cols 0..15 per row)
  __shared__ float csm[128][2];                      // 1 KB  (cin, cfg per row)

  const int tid   = threadIdx.x;
  const int lane  = tid & 63;
  const int w     = tid >> 6;          // wave = mblock
  const int rb    = blockIdx.x;
  const int s     = blockIdx.y;
  const int d     = blockIdx.z;
  const int col   = lane & 31;
  const int khalf = lane >> 5;

  const int isf    = meta[0];
  const int len_s  = meta[8 + b];
  const int base_s = meta[40 + b];

  // bias preloads (L1/L2 hits)
  float bg[4];
  #pragma unroll
  for (int f = 0; f < 4; ++f) bg[f] = bsum[16 + f * H_ + s * 32 + col];
  const float c0b = (col < 16) ? bsum[col] : 0.f;

  f32x16 acc[NF];
  #pragma unroll
  for (int f = 0; f < NF; ++f)
    #pragma unroll
    for (int r = 0; r < 16; ++r) acc[f][r] = 0.f;

  const bf16* wswKb = Wsw + (((size_t)d * NSL + s) * NKB) * (NF * 512);

  // stage chunk 0
  {
    const bf16* src = wswKb;
    *(short8*)&Bsm[0][w][lane * 8] = *(const short8*)(src + (w * 64 + lane) * 8);
    if (w == 0)
      *(short8*)&Bsm[0][4][lane * 8] = *(const short8*)(src + (256 + lane) * 8);
  }

  for (int kb = 0; kb < NKB; ++kb) {
    const int cur = kb & 1;
    __syncthreads();   // Bsm[cur] visible; prior reads of Bsm[cur^1] done

    // A frag (direct from swizzled global; one coalesced 1 KB load per wave)
    const bf16* aPtr = (kb < 16)
        ? xs + ((((size_t)b * NRB + rb) * 16 + kb) * NMB + w) * 512 + lane * 8
        : hs + ((((size_t)d * NRB + rb) * 16 + (kb - 16)) * NMB + w) * 512 + lane * 8;
    short8 af = *(const short8*)aPtr;

    // stage next W chunk into regs (overlaps MFMAs below)
    short8 nx0{}, nx1{};
    if (kb + 1 < NKB) {
      const bf16* src = wswKb + (size_t)(kb + 1) * (NF * 512);
      nx0 = *(const short8*)(src + (w * 64 + lane) * 8);
      if (w == 0) nx1 = *(const short8*)(src + (256 + lane) * 8);
    }

    #pragma unroll
    for (int f = 0; f < NF; ++f) {
      short8 bfr = *(const short8*)&Bsm[cur][f][lane * 8];
      acc[f] = __builtin_amdgcn_mfma_f32_32x32x16_bf16(af, bfr, acc[f], 0, 0, 0);
    }

    if (kb + 1 < NKB) {
      *(short8*)&Bsm[cur ^ 1][w][lane * 8] = nx0;
      if (w == 0) *(short8*)&Bsm[cur ^ 1][4][lane * 8] = nx1;
    }
  }

  // ---- epilogue ----
  // 32x32x16 C layout: col = lane&31, row = (r&3) + 8*(r>>2) + 4*(lane>>5)
  if (col < 16) {
    #pragma unroll
    for (int r = 0; r < 16; ++r) {
      const int row = (r & 3) + 8 * (r >> 2) + 4 * khalf;
      gsm[w * 32 + row][col] = acc[4][r] + c0b;
    }
  }
  __syncthreads();

  if (tid < 128) {
    float g[16];
    #pragma unroll
    for (int i = 0; i < 16; ++i) g[i] = gsm[tid][i];
    float m1 = g[0], m2 = g[8];
    #pragma unroll
    for (int i = 1; i < 8; ++i) { m1 = fmaxf(m1, g[i]); m2 = fmaxf(m2, g[8 + i]); }
    float S1 = 0.f, P1 = 0.f, S2 = 0.f, P2 = 0.f;
    #pragma unroll
    for (int i = 0; i < 8; ++i) {
      float e1 = __expf(g[i] - m1);     S1 += e1; if (i <= s) P1 += e1;
      float e2 = __expf(g[8 + i] - m2); S2 += e2; if (i <= s) P2 += e2;
    }
    csm[tid][0] = 1.f - P1 / S1;   // cin for chunk n == s
    csm[tid][1] = P2 / S2;         // cfg
  }
  __syncthreads();

  // cell math per lane-reg
  float* csP = cs + ((((size_t)d * NSL + s) * NRB + rb) * NMB + w) * 1024; // [reg][lane]
  const int e   = s * 32 + col;
  const int k8e = (e >> 3) & 1, ele = e & 7, kbh = e >> 4;
  bf16* hsBase = hs + ((((size_t)d * NRB + rb) * 16 + kbh) * NMB + w) * 512;

  #pragma unroll
  for (int r = 0; r < 16; ++r) {
    const int row = (r & 3) + 8 * (r >> 2) + 4 * khalf;
    const float cin = csm[w * 32 + row][0];
    const float cfg = csm[w * 32 + row][1];
    const float og = sigmoidf_(acc[0][r] + bg[0]);
    const float cg = tanh_   (acc[1][r] + bg[1]);
    const float ig = sigmoidf_(acc[2][r] + bg[2]);
    const float fg = sigmoidf_(acc[3][r] + bg[3]);
    const float ov = cfg * cin;
    const float f2 = fg * ov + (cfg - ov);
    const float i2 = ig * ov + (cin - ov);
    const float cprev = csP[r * 64 + lane];
    const float cy = f2 * cprev + i2 * cg;
    csP[r * 64 + lane] = cy;
    const float hy = og * tanh_(cy);
    hsBase[(size_t)(row + 32 * k8e) * 8 + ele] = __float2bfloat16(hy);
    const int t = rb * 128 + w * 32 + row;
    if (t < len_s) {
      const size_t o = (size_t)(base_s + t) * (2 * H_) + (size_t)d * H_ + e;
      if (isf) ((float*)out)[o] = hy;
      else     ((bf16*)out)[o]  = __float2bfloat16(hy);
    }
  }
}

// ---------------------------------------------------------------------------
extern "C" void kernel_launch(void* const* d_in, const int* in_sizes, int n_in,
                              void* d_out, int out_size, void* d_ws, size_t ws_size,
                              hipStream_t stream)
{
  const void* x    = d_in[0];
  const int*  sl   = (const int*)d_in[1];
  const void* W_ih = d_in[2];
  const void* b_ih = d_in[3];
  const void* W_hh = d_in[4];
  const void* b_hh = d_in[5];

  char* ws = (char*)d_ws;
  size_t off = 0;
  auto alloc = [&](size_t bytes) {
    void* p = ws + off;
    off = (off + bytes + 255) & ~(size_t)255;
    return p;
  };
  int*   meta = (int*)  alloc(128 * sizeof(int));
  bf16*  xs   = (bf16*) alloc((size_t)B_ * T_ * D_ * sizeof(bf16));        // 32 MB
  bf16*  Wsw  = (bf16*) alloc((size_t)2 * NSL * NKB * NF * 512 * sizeof(bf16)); // 2.6 MB
  bf16*  hs   = (bf16*) alloc((size_t)2 * T_ * H_ * sizeof(bf16));         // 2 MB
  float* cs   = (float*)alloc((size_t)2 * T_ * H_ * sizeof(float));        // 4 MB
  float* bsum = (float*)alloc((size_t)G_ * sizeof(float));

  hipMemsetAsync(hs, 0, (size_t)2 * T_ * H_ * sizeof(bf16), stream);
  hipMemsetAsync(cs, 0, (size_t)2 * T_ * H_ * sizeof(float), stream);

  detect_prep<<<1, 256, 0, stream>>>((const unsigned short*)x, sl, meta);
  build_bsum<<<(G_ + 255) / 256, 256, 0, stream>>>(b_ih, b_hh, bsum, meta);
  build_xs<<<(int)(((size_t)B_ * T_ * D_ / 8 + 255) / 256), 256, 0, stream>>>(x, xs, meta);
  build_wsw<<<(2 * NSL * NKB * NF * 64 + 255) / 256, 256, 0, stream>>>(W_ih, W_hh, Wsw, meta);

  for (int b = 0; b < B_; ++b)
    step_fused<<<dim3(NRB, NSL, 2), 256, 0, stream>>>(xs, Wsw, hs, cs, bsum, d_out, meta, b);
}